// Round 6
// baseline (80824.481 us; speedup 1.0000x reference)
//
#include <hip/hip_runtime.h>
#include <hip/hip_bf16.h>

typedef __hip_bfloat16 bf16;
typedef unsigned short u16;
typedef unsigned int u32;

#define D1c 48
#define H1c 40
#define W1c 48
#define NHALF 92160L
#define D2c 96
#define H2c 80
#define W2c 96
#define NFULL 737280L
#define S1 368
#define S2 128
#define RG 512

#define NX1 (NHALF * S1)
#define NX2 (NFULL * S2)
#define NCTX16 (NHALF * 16)
#define N3H (NHALF * 3)
#define N3F (NFULL * 3)

__device__ __forceinline__ float bf2f(bf16 v){ return __bfloat162float(v); }
__device__ __forceinline__ float sf(float v){ return (v == v && fabsf(v) < 1e30f) ? v : 0.f; }
__device__ __forceinline__ bf16 f2bf(float v){ return __float2bfloat16(sf(v)); }
__device__ __forceinline__ long cl(long i, long n){ i = i < 0 ? 0 : i; return i >= n ? n - 1 : i; }
// mode-dispatched input load: 0 = bf16, 1 = f32
__device__ __forceinline__ float gld(const void* p, long i, int mode){
    return mode ? sf(((const float*)p)[i]) : sf(bf2f(((const bf16*)p)[i]));
}

// ---------------- dtype detection: one block per input ---------------------
__global__ void k_detect(const void* p, long nelem, int* flag) {
    long N = nelem < 4096 ? nelem : 4096;
    int tid = threadIdx.x;
    int nb = 0, nf = 0;
    for (long i = tid; i < N; i += 256) {
        float v = bf2f(((const bf16*)p)[i]);
        if (v == v && fabsf(v) <= 1e4f) nb++;
    }
    long M = N / 2;
    for (long i = tid; i < M; i += 256) {
        float v = ((const float*)p)[i];
        if (v == v && fabsf(v) <= 1e4f) nf += 2;
    }
    __shared__ int sb[256], sq[256];
    sb[tid] = nb; sq[tid] = nf;
    __syncthreads();
    for (int t = 128; t; t >>= 1) {
        if (tid < t) { sb[tid] += sb[tid + t]; sq[tid] += sq[tid + t]; }
        __syncthreads();
    }
    if (tid == 0) *flag = (sb[0] >= sq[0]) ? 0 : 1;
}

// ---------------- fills -----------------------------------------------------
__global__ void k_fill(u16* __restrict__ p, long n, u16 val) {
    long i = (long)blockIdx.x * 256 + threadIdx.x;
    long stride = (long)gridDim.x * 256;
    for (; i < n; i += stride) p[i] = val;
}
__global__ void k_fill_tail(void* out, long vf, long out_n, const int* __restrict__ modep) {
    int mode = *modep;
    long n = out_n - vf;
    if (n <= 0) return;
    long i = (long)blockIdx.x * 256 + threadIdx.x;
    long stride = (long)gridDim.x * 256;
    if (mode) { float* p = (float*)out + vf; for (; i < n; i += stride) p[i] = 0.f; }
    else      { u16*   p = (u16*)out + vf;   for (; i < n; i += stride) p[i] = 0; }
}

// ------- weight transpose: (co,ci,tap) -> (tap,ci,co) f32 ------------------
__global__ void k_wt(const void* __restrict__ w, float* __restrict__ wt,
                     int Cin, int Cout, const int* __restrict__ modep) {
    int mode = *modep;
    long n = (long)Cin * Cout * 27;
    long i = (long)blockIdx.x * 256 + threadIdx.x;
    if (i >= n) return;
    int tap = (int)(i % 27); long r = i / 27;
    int ci = (int)(r % Cin); int co = (int)(r / Cin);
    wt[cl(((long)tap * Cin + ci) * Cout + co, n)] = gld(w, cl(i, n), mode);
}

// ------- channel-first [C][N] -> channel-last columns ----------------------
__global__ void k_tcl(const void* __restrict__ in, long nin,
                      bf16* __restrict__ out, long nout, int col0,
                      int C, long N, int stride, const int* __restrict__ modep) {
    int mode = *modep;
    long n = (long)blockIdx.x * 256 + threadIdx.x;
    if (n >= N) return;
    for (int c = 0; c < C; ++c)
        out[cl(n * stride + col0 + c, nout)] = f2bf(gld(in, cl((long)c * N + n, nin), mode));
}

// ------- antialiased x0.5 downsample taps ----------------------------------
__device__ __forceinline__ void down_taps(int i, int n_in, int j[4], float w[4]) {
    float s = 0.f;
    for (int k = 0; k < 4; ++k) {
        int jj = 2 * i - 1 + k;
        bool valid = (jj >= 0 && jj < n_in);
        j[k] = valid ? jj : 0;
        float b = (k == 0 || k == 3) ? 1.f : 3.f;
        w[k] = valid ? b : 0.f;
        s += w[k];
    }
    float inv = 1.f / fmaxf(s, 1e-6f);
    for (int k = 0; k < 4; ++k) w[k] *= inv;
}

// disp = resize(disp_up,0.5)*0.5 -> disph f32 + xin1 cols 221..223
__global__ void k_down(const void* __restrict__ dispup, float* __restrict__ disph,
                       bf16* __restrict__ xin1, const int* __restrict__ modep) {
    int mode = *modep;
    long p = (long)blockIdx.x * 256 + threadIdx.x;
    if (p >= NHALF) return;
    int x = (int)(p % W1c), y = (int)((p / W1c) % H1c), z = (int)(p / (W1c * H1c));
    int jz[4], jy[4], jx[4]; float wz[4], wy[4], wx[4];
    down_taps(z, D2c, jz, wz); down_taps(y, H2c, jy, wy); down_taps(x, W2c, jx, wx);
    for (int c = 0; c < 3; ++c) {
        float acc = 0.f;
        for (int a = 0; a < 4; ++a) {
            if (wz[a] == 0.f) continue;
            for (int b = 0; b < 4; ++b) {
                if (wy[b] == 0.f) continue;
                float wzy = wz[a] * wy[b];
                long base = (long)c * NFULL + ((long)jz[a] * H2c + jy[b]) * W2c;
                for (int d = 0; d < 4; ++d) {
                    if (wx[d] == 0.f) continue;
                    acc += wzy * wx[d] * gld(dispup, cl(base + jx[d], 3 * NFULL), mode);
                }
            }
        }
        acc = sf(acc * 0.5f);
        disph[cl(p * 3 + c, N3H)] = acc;
        xin1[cl(p * (long)S1 + 221 + c, NX1)] = f2bf(acc);
    }
}

// ------- trilinear warp, channel-first INPUT volume, zero pad --------------
template<int C>
__global__ void k_warp_cf(const void* __restrict__ vol, long nvol,
                          const float* __restrict__ coords, long ncoords,
                          bf16* __restrict__ dst, long ndst, int dstride, int col0,
                          int D, int H, int W, const int* __restrict__ modep) {
    int mode = *modep;
    const long N = (long)D * H * W;
    long p = (long)blockIdx.x * 256 + threadIdx.x;
    if (p >= N) return;
    int x = (int)(p % W), y = (int)((p / W) % H), z = (int)(p / ((long)W * H));
    float cz = z + sf(coords[cl(p * 3, ncoords)]);
    float cy = y + sf(coords[cl(p * 3 + 1, ncoords)]);
    float cx = x + sf(coords[cl(p * 3 + 2, ncoords)]);
    float acc[C];
    for (int c = 0; c < C; ++c) acc[c] = 0.f;
    float z0f = floorf(cz), y0f = floorf(cy), x0f = floorf(cx);
    int z0 = (int)z0f, y0 = (int)y0f, x0 = (int)x0f;
    float fz = cz - z0f, fy = cy - y0f, fx = cx - x0f;
    for (int dz = 0; dz < 2; ++dz) {
        int zi = z0 + dz; if (zi < 0 || zi >= D) continue;
        float wz = dz ? fz : 1.f - fz;
        for (int dy = 0; dy < 2; ++dy) {
            int yi = y0 + dy; if (yi < 0 || yi >= H) continue;
            float wzy = wz * (dy ? fy : 1.f - fy);
            for (int dx = 0; dx < 2; ++dx) {
                int xi = x0 + dx; if (xi < 0 || xi >= W) continue;
                float w = wzy * (dx ? fx : 1.f - fx);
                long idx = (long)(zi * H + yi) * W + xi;
                for (int c = 0; c < C; ++c) acc[c] += w * gld(vol, cl((long)c * N + idx, nvol), mode);
            }
        }
    }
    for (int c = 0; c < C; ++c) dst[cl(p * (long)dstride + col0 + c, ndst)] = f2bf(acc[c]);
}

// ------- two-stage deterministic reduction (sum, sumsq) --------------------
__global__ void k_reduce_cl(const void* __restrict__ base, long nbase, long rows,
                            int stride, int col0, int cn, double* __restrict__ part,
                            const int* __restrict__ modep) {
    int mode = *modep;
    long total = rows * cn;
    double s = 0.0, q = 0.0;
    long i = (long)blockIdx.x * 256 + threadIdx.x;
    long gs = (long)gridDim.x * 256;
    for (; i < total; i += gs) {
        long r = i / cn; int c = (int)(i - r * cn);
        float f = gld(base, cl(r * (long)stride + col0 + c, nbase), mode);
        s += f; q += (double)f * f;
    }
    __shared__ double ls[256], lq[256];
    ls[threadIdx.x] = s; lq[threadIdx.x] = q;
    __syncthreads();
    for (int t = 128; t; t >>= 1) {
        if (threadIdx.x < t) { ls[threadIdx.x] += ls[threadIdx.x + t]; lq[threadIdx.x] += lq[threadIdx.x + t]; }
        __syncthreads();
    }
    if (threadIdx.x == 0) { part[cl(blockIdx.x * 2, RG * 2)] = ls[0]; part[cl(blockIdx.x * 2 + 1, RG * 2)] = lq[0]; }
}

__global__ void k_stats2(const double* __restrict__ pa, const double* __restrict__ pb,
                         double n, double C, double* __restrict__ outm) {
    __shared__ double ls[256], lq[256];
    double s = 0.0, q = 0.0;
    for (int i = threadIdx.x; i < RG; i += 256) { s += pa[i * 2]; q += pa[i * 2 + 1]; }
    ls[threadIdx.x] = s; lq[threadIdx.x] = q;
    __syncthreads();
    for (int t = 128; t; t >>= 1) {
        if (threadIdx.x < t) { ls[threadIdx.x] += ls[threadIdx.x + t]; lq[threadIdx.x] += lq[threadIdx.x + t]; }
        __syncthreads();
    }
    double sa = ls[0], qa = lq[0];
    __syncthreads();
    s = 0.0; q = 0.0;
    for (int i = threadIdx.x; i < RG; i += 256) { s += pb[i * 2]; q += pb[i * 2 + 1]; }
    ls[threadIdx.x] = s; lq[threadIdx.x] = q;
    __syncthreads();
    for (int t = 128; t; t >>= 1) {
        if (threadIdx.x < t) { ls[threadIdx.x] += ls[threadIdx.x + t]; lq[threadIdx.x] += lq[threadIdx.x + t]; }
        __syncthreads();
    }
    if (threadIdx.x == 0) {
        double sb = ls[0], qb = lq[0];
        double va = (qa - sa * sa / n) / (n - 1.0);
        double vb = (qb - sb * sb / n) / (n - 1.0);
        va = va > 0.0 ? va : 0.0;
        vb = vb > 0.0 ? vb : 0.0;
        double sd = 0.5 * (sqrt(va) + sqrt(vb));
        sd = sd < 1e-6 ? 1e-6 : (sd > 1e9 ? 1e9 : sd);
        outm[0] = 0.5 * (sa / n + sb / n);
        outm[1] = 1.0 / (sd * sd * C);
    }
}

// ------- cost volume 1 (md=2, C=32) -> xin1 cols 0..124 --------------------
__global__ void k_cv1(bf16* __restrict__ xin1, const double* __restrict__ red) {
    __shared__ float fy[32];
    long p = blockIdx.x;
    float m = sf((float)red[0]), mult = sf((float)red[1]);
    int x = (int)(p % W1c), y = (int)((p / W1c) % H1c), z = (int)(p / (W1c * H1c));
    if (threadIdx.x < 32) fy[threadIdx.x] = sf(bf2f(xin1[cl(p * (long)S1 + 125 + threadIdx.x, NX1)])) - m;
    __syncthreads();
    int o = threadIdx.x;
    if (o >= 125) return;
    int dz = o / 25 - 2, dy = (o / 5) % 5 - 2, dx = o % 5 - 2;
    int z2 = z + dz, y2 = y + dy, x2 = x + dx;
    float cost = 0.f;
    if (z2 >= 0 && z2 < D1c && y2 >= 0 && y2 < H1c && x2 >= 0 && x2 < W1c) {
        long rb = ((long)(z2 * H1c + y2) * W1c + x2) * S1 + 157;
        float dot = 0.f;
        for (int c = 0; c < 32; ++c) dot += fy[c] * (sf(bf2f(xin1[cl(rb + c, NX1)])) - m);
        cost = dot * mult;
        cost = cost >= 0.f ? cost : 0.05f * cost;
    }
    xin1[cl(p * (long)S1 + o, NX1)] = f2bf(cost);
}

// ------- cost volume 2 (md=1, C=16) -> xin2 cols 0..26 ---------------------
__global__ void k_cv2(bf16* __restrict__ xin2, const double* __restrict__ red) {
    int t = threadIdx.x;
    int o = t % 32, vs = t / 32;
    long p = (long)blockIdx.x * 8 + vs;
    if (p >= NFULL || o >= 27) return;
    float m = sf((float)red[2]), mult = sf((float)red[3]);
    int x = (int)(p % W2c), y = (int)((p / W2c) % H2c), z = (int)(p / (W2c * H2c));
    int dz = o / 9 - 1, dy = (o / 3) % 3 - 1, dx = o % 3 - 1;
    int z2 = z + dz, y2 = y + dy, x2 = x + dx;
    float cost = 0.f;
    if (z2 >= 0 && z2 < D2c && y2 >= 0 && y2 < H2c && x2 >= 0 && x2 < W2c) {
        long fb = p * (long)S2 + 27;
        long wb = ((long)(z2 * H2c + y2) * W2c + x2) * S2 + 43;
        float dot = 0.f;
        for (int c = 0; c < 16; ++c)
            dot += (sf(bf2f(xin2[cl(fb + c, NX2)])) - m) * (sf(bf2f(xin2[cl(wb + c, NX2)])) - m);
        cost = dot * mult;
        cost = cost >= 0.f ? cost : 0.05f * cost;
    }
    xin2[cl(p * (long)S2 + o, NX2)] = f2bf(cost);
}

// ------- direct 3x3x3 conv, channel-last internal bf16, clamped ------------
template<int CO_PAD, int VPT>
__global__ __launch_bounds__(256) void k_conv(
        const bf16* __restrict__ src, long nsrc, int sstride,
        const float* __restrict__ wt, const void* __restrict__ bias,
        bf16* __restrict__ dst, long ndst, int dstride, int dcol0,
        int Cin, int Cout, int D, int H, int W, float slope,
        const int* __restrict__ bmodep) {
    int bmode = *bmodep;
    constexpr int SUBS = 256 / CO_PAD;
    constexpr int CI = 16;
    __shared__ float wl[CI * CO_PAD];
    const int tid = threadIdx.x;
    const int co = tid % CO_PAD;
    const int sub = tid / CO_PAD;
    const long N = (long)D * H * W;
    const long nwt = 27L * Cin * Cout;
    const bool alive = (sub < SUBS);
    const long vox0 = ((long)blockIdx.x * SUBS + (alive ? sub : 0)) * VPT;

    int zz[VPT], yy[VPT], xx[VPT];
    for (int v = 0; v < VPT; ++v) {
        long p = vox0 + v;
        if (alive && p < N) {
            xx[v] = (int)(p % W); long r = p / W; yy[v] = (int)(r % H); zz[v] = (int)(r / H);
        } else { zz[v] = -1000000; yy[v] = 0; xx[v] = 0; }
    }
    float acc[VPT];
    float bv = (co < Cout) ? gld(bias, co, bmode) : 0.f;
    for (int v = 0; v < VPT; ++v) acc[v] = bv;

    const int nchunk = (Cin + CI - 1) / CI;
    for (int tap = 0; tap < 27; ++tap) {
        int dz = tap / 9 - 1, dy = (tap / 3) % 3 - 1, dx = tap % 3 - 1;
        long nb[VPT];
        for (int v = 0; v < VPT; ++v) {
            int z2 = zz[v] + dz, y2 = yy[v] + dy, x2 = xx[v] + dx;
            nb[v] = (z2 >= 0 && z2 < D && y2 >= 0 && y2 < H && x2 >= 0 && x2 < W)
                    ? ((long)(z2 * H + y2) * W + x2) : -1L;
        }
        for (int cc = 0; cc < nchunk; ++cc) {
            int ci0 = cc * CI;
            __syncthreads();
            for (int e = tid; e < CI * CO_PAD; e += 256) {
                int ci = ci0 + e / CO_PAD; int c = e % CO_PAD;
                wl[e] = (ci < Cin && c < Cout) ? wt[cl(((long)tap * Cin + ci) * (long)Cout + c, nwt)] : 0.f;
            }
            __syncthreads();
            #pragma unroll
            for (int ci = 0; ci < CI; ++ci) {
                float wv = wl[ci * CO_PAD + co];
                for (int v = 0; v < VPT; ++v) {
                    float f = (nb[v] >= 0 && ci0 + ci < Cin)
                            ? bf2f(src[cl(nb[v] * (long)sstride + ci0 + ci, nsrc)]) : 0.f;
                    acc[v] += f * wv;
                }
            }
        }
    }
    for (int v = 0; v < VPT; ++v) {
        long p = vox0 + v;
        if (alive && p < N && co < Cout) {
            float o = acc[v];
            o = o >= 0.f ? o : o * slope;
            dst[cl(p * (long)dstride + dcol0 + co, ndst)] = f2bf(o);
        }
    }
}

// ------- small conv: Cin=16 -> Cout=3, linear, f32 out ---------------------
__global__ void k_conv_small(const bf16* __restrict__ src, long nsrc, int sstride, int scol0,
                             const float* __restrict__ wt, const void* __restrict__ bias,
                             float* __restrict__ dst, long ndst, int D, int H, int W,
                             const int* __restrict__ bmodep) {
    int bmode = *bmodep;
    __shared__ float wl[27 * 16 * 3];
    for (int e = threadIdx.x; e < 27 * 16 * 3; e += 256) wl[e] = wt[e];
    __syncthreads();
    long N = (long)D * H * W;
    long p = (long)blockIdx.x * 256 + threadIdx.x;
    if (p >= N) return;
    int x = (int)(p % W), y = (int)((p / W) % H), z = (int)(p / ((long)W * H));
    float a0 = gld(bias, 0, bmode), a1 = gld(bias, 1, bmode), a2 = gld(bias, 2, bmode);
    for (int tap = 0; tap < 27; ++tap) {
        int dz = tap / 9 - 1, dy = (tap / 3) % 3 - 1, dx = tap % 3 - 1;
        int z2 = z + dz, y2 = y + dy, x2 = x + dx;
        if (z2 < 0 || z2 >= D || y2 < 0 || y2 >= H || x2 < 0 || x2 >= W) continue;
        long rb = ((long)(z2 * H + y2) * W + x2) * sstride + scol0;
        const float* w = wl + tap * 48;
        for (int c = 0; c < 16; ++c) {
            float f = bf2f(src[cl(rb + c, nsrc)]);
            a0 += f * w[c * 3]; a1 += f * w[c * 3 + 1]; a2 += f * w[c * 3 + 2];
        }
    }
    dst[cl(p * 3, ndst)] = sf(a0); dst[cl(p * 3 + 1, ndst)] = sf(a1); dst[cl(p * 3 + 2, ndst)] = sf(a2);
}

// ------- x2 upsample taps ---------------------------------------------------
__device__ __forceinline__ void up_taps(int i, int n, int& j0, int& j1, float& w0, float& w1) {
    if (i & 1) { j0 = i >> 1; j1 = j0 + 1; w0 = 0.75f; w1 = 0.25f; if (j1 >= n) { j1 = j0; w0 = 1.f; w1 = 0.f; } }
    else { j1 = i >> 1; j0 = j1 - 1; w0 = 0.25f; w1 = 0.75f; if (j0 < 0) { j0 = j1; w0 = 0.f; w1 = 1.f; } }
}

// ctx16 [NHALF][16] -> xin2 cols 59..74
__global__ void k_up_ctx(const bf16* __restrict__ in, bf16* __restrict__ xin2) {
    long p = (long)blockIdx.x * 256 + threadIdx.x;
    if (p >= NFULL) return;
    int x = (int)(p % W2c), y = (int)((p / W2c) % H2c), z = (int)(p / (W2c * H2c));
    int jz0, jz1, jy0, jy1, jx0, jx1; float wz0, wz1, wy0, wy1, wx0, wx1;
    up_taps(z, D1c, jz0, jz1, wz0, wz1);
    up_taps(y, H1c, jy0, jy1, wy0, wy1);
    up_taps(x, W1c, jx0, jx1, wx0, wx1);
    float acc[16];
    for (int c = 0; c < 16; ++c) acc[c] = 0.f;
    int jzs[2] = { jz0, jz1 }; float wzs[2] = { wz0, wz1 };
    int jys[2] = { jy0, jy1 }; float wys[2] = { wy0, wy1 };
    int jxs[2] = { jx0, jx1 }; float wxs[2] = { wx0, wx1 };
    for (int a = 0; a < 2; ++a) {
        if (wzs[a] == 0.f) continue;
        for (int b = 0; b < 2; ++b) {
            if (wys[b] == 0.f) continue;
            float wzy = wzs[a] * wys[b];
            for (int d = 0; d < 2; ++d) {
                if (wxs[d] == 0.f) continue;
                float w = wzy * wxs[d];
                long rb = ((long)(jzs[a] * H1c + jys[b]) * W1c + jxs[d]) * 16;
                for (int c = 0; c < 16; ++c) acc[c] += w * bf2f(in[cl(rb + c, NCTX16)]);
            }
        }
    }
    for (int c = 0; c < 16; ++c) xin2[cl(p * (long)S2 + 59 + c, NX2)] = f2bf(acc[c]);
}

// fused: velup = 2*up(vel1); du2 = warp(disp_up, velup) + velup; xin2 75..77
__global__ void k_warp_dispup(const void* __restrict__ dispup, const float* __restrict__ vel1,
                              float* __restrict__ du2, bf16* __restrict__ xin2,
                              const int* __restrict__ modep) {
    int mode = *modep;
    long p = (long)blockIdx.x * 256 + threadIdx.x;
    if (p >= NFULL) return;
    int x = (int)(p % W2c), y = (int)((p / W2c) % H2c), z = (int)(p / (W2c * H2c));
    int jz0, jz1, jy0, jy1, jx0, jx1; float wz0, wz1, wy0, wy1, wx0, wx1;
    up_taps(z, D1c, jz0, jz1, wz0, wz1);
    up_taps(y, H1c, jy0, jy1, wy0, wy1);
    up_taps(x, W1c, jx0, jx1, wx0, wx1);
    int jzs[2] = { jz0, jz1 }; float wzs[2] = { wz0, wz1 };
    int jys[2] = { jy0, jy1 }; float wys[2] = { wy0, wy1 };
    int jxs[2] = { jx0, jx1 }; float wxs[2] = { wx0, wx1 };
    float vu[3] = { 0.f, 0.f, 0.f };
    for (int a = 0; a < 2; ++a) {
        if (wzs[a] == 0.f) continue;
        for (int b = 0; b < 2; ++b) {
            if (wys[b] == 0.f) continue;
            float wzy = wzs[a] * wys[b];
            for (int d = 0; d < 2; ++d) {
                if (wxs[d] == 0.f) continue;
                float w = wzy * wxs[d];
                long rb = ((long)(jzs[a] * H1c + jys[b]) * W1c + jxs[d]) * 3;
                for (int c = 0; c < 3; ++c) vu[c] += w * sf(vel1[cl(rb + c, N3H)]);
            }
        }
    }
    for (int c = 0; c < 3; ++c) vu[c] = sf(vu[c] * 2.f);
    float cz = z + vu[0], cy = y + vu[1], cx = x + vu[2];
    float acc[3] = { 0.f, 0.f, 0.f };
    float z0f = floorf(cz), y0f = floorf(cy), x0f = floorf(cx);
    int z0 = (int)z0f, y0 = (int)y0f, x0 = (int)x0f;
    float fz = cz - z0f, fy = cy - y0f, fx = cx - x0f;
    for (int dz = 0; dz < 2; ++dz) {
        int zi = z0 + dz; if (zi < 0 || zi >= D2c) continue;
        float wz = dz ? fz : 1.f - fz;
        for (int dy = 0; dy < 2; ++dy) {
            int yi = y0 + dy; if (yi < 0 || yi >= H2c) continue;
            float wzy = wz * (dy ? fy : 1.f - fy);
            for (int dx = 0; dx < 2; ++dx) {
                int xi = x0 + dx; if (xi < 0 || xi >= W2c) continue;
                float w = wzy * (dx ? fx : 1.f - fx);
                long idx = (long)(zi * H2c + yi) * W2c + xi;
                for (int c = 0; c < 3; ++c) acc[c] += w * gld(dispup, cl((long)c * NFULL + idx, 3 * NFULL), mode);
            }
        }
    }
    for (int c = 0; c < 3; ++c) {
        float v = sf(acc[c] + vu[c]);
        du2[cl(p * 3 + c, N3F)] = v;
        xin2[cl(p * (long)S2 + 75 + c, NX2)] = f2bf(v);
    }
}

// robust t decode (handles bf16-stored or f32-stored scalar)
__device__ __forceinline__ float decode_t(const u16* tp) {
    u16 b0 = tp[0], b1 = tp[1];
    union { u32 i; float f; } a, b;
    a.i = ((u32)b0) << 16;
    b.i = ((u32)b1 << 16) | b0;
    float ta = a.f, tb = b.f;
    bool okA = (ta == ta) && ta >= 0.f && ta < 0.75f;
    bool okB = (tb == tb) && tb >= 0.f && tb < 0.75f;
    return okB ? tb : (okA ? ta : 0.f);
}

// vf = (warp(du2, vu2) + vu2 - disp_up) / (1 - t); out mode-dispatched
__global__ void k_final(const float* __restrict__ du2, const float* __restrict__ vu2,
                        const void* __restrict__ dispup, const u16* __restrict__ tptr,
                        void* __restrict__ out, long out_n, const int* __restrict__ modep) {
    int mode = *modep;
    long p = (long)blockIdx.x * 256 + threadIdx.x;
    if (p >= NFULL) return;
    float t = decode_t(tptr);
    float den = 1.f - t;
    if (fabsf(den) < 1e-6f) den = 1e-6f;
    float inv = 1.f / den;
    int x = (int)(p % W2c), y = (int)((p / W2c) % H2c), z = (int)(p / (W2c * H2c));
    float cz = z + sf(vu2[cl(p * 3, N3F)]);
    float cy = y + sf(vu2[cl(p * 3 + 1, N3F)]);
    float cx = x + sf(vu2[cl(p * 3 + 2, N3F)]);
    float acc[3] = { 0.f, 0.f, 0.f };
    float z0f = floorf(cz), y0f = floorf(cy), x0f = floorf(cx);
    int z0 = (int)z0f, y0 = (int)y0f, x0 = (int)x0f;
    float fz = cz - z0f, fy = cy - y0f, fx = cx - x0f;
    for (int dz = 0; dz < 2; ++dz) {
        int zi = z0 + dz; if (zi < 0 || zi >= D2c) continue;
        float wz = dz ? fz : 1.f - fz;
        for (int dy = 0; dy < 2; ++dy) {
            int yi = y0 + dy; if (yi < 0 || yi >= H2c) continue;
            float wzy = wz * (dy ? fy : 1.f - fy);
            for (int dx = 0; dx < 2; ++dx) {
                int xi = x0 + dx; if (xi < 0 || xi >= W2c) continue;
                float w = wzy * (dx ? fx : 1.f - fx);
                long rb = ((long)(zi * H2c + yi) * W2c + xi) * 3;
                for (int c = 0; c < 3; ++c) acc[c] += w * sf(du2[cl(rb + c, N3F)]);
            }
        }
    }
    for (int c = 0; c < 3; ++c) {
        float v = (acc[c] + sf(vu2[cl(p * 3 + c, N3F)]) - gld(dispup, cl((long)c * NFULL + p, 3 * NFULL), mode)) * inv;
        long oi = cl((long)c * NFULL + p, out_n);
        if (mode) ((float*)out)[oi] = sf(v);
        else      ((bf16*)out)[oi] = f2bf(v);
    }
}

static inline int cdiv(long a, long b) { return (int)((a + b - 1) / b); }

extern "C" void kernel_launch(void* const* d_in, const int* in_sizes, int n_in,
                              void* d_out, int out_size, void* d_ws, size_t ws_size,
                              hipStream_t stream) {
    const u16* t_in = (const u16*)d_in[0];
    const void* disp_up = d_in[1];
    const void* fx  = d_in[2];
    const void* fy  = d_in[3];
    const void* fxu = d_in[4];
    const void* fyu = d_in[5];
    const void* ctx = d_in[6];

    const size_t XIN1_B = (size_t)NX1 * 2;
    const size_t XIN2_B = (size_t)NX2 * 2;
    const size_t base_need = XIN1_B + XIN2_B;
    const size_t base_pad = (base_need + 255) & ~(size_t)255;
    const size_t vf_elems = 3UL * NFULL;

    size_t scro[10];
    {
        size_t o = 0;
        auto al = [&](size_t bytes) { size_t r = o; o = (o + bytes + 255) & ~(size_t)255; return r; };
        scro[0] = al(1327104UL * 4);            // WT
        scro[1] = al((size_t)NCTX16 * 2);       // CTX16
        scro[2] = al((size_t)N3H * 4);          // VEL1
        scro[3] = al((size_t)N3H * 4);          // DISPH
        scro[4] = al((size_t)N3F * 4);          // DU2
        scro[5] = al((size_t)N3F * 4);          // VU2
        scro[6] = al(4UL * RG * 2 * 8);         // partials
        scro[7] = al(16 * 8);                   // RED
        scro[8] = al(32 * 4);                   // MODES
        scro[9] = o;
    }
    const size_t scratch_need = scro[9];
    const size_t tail_avail = ((size_t)out_size > vf_elems) ? ((size_t)out_size - vf_elems) * 2 : 0;

    char* scr = nullptr;
    if (ws_size >= base_pad + scratch_need) {
        scr = (char*)d_ws + base_pad;
    } else if (ws_size >= base_need && tail_avail >= scratch_need) {
        scr = (char*)d_out + vf_elems * 2;
    }
    if (scr == nullptr) {
        k_fill<<<2048, 256, 0, stream>>>((u16*)d_out, (long)out_size, 0x49A0);
        return;
    }

    char* ws = (char*)d_ws;
    bf16*  xin1  = (bf16*)ws;
    bf16*  xin2  = (bf16*)(ws + XIN1_B);
    float* wtall = (float*)(scr + scro[0]);
    bf16*  ctx16 = (bf16*)(scr + scro[1]);
    float* vel1  = (float*)(scr + scro[2]);
    float* disph = (float*)(scr + scro[3]);
    float* du2   = (float*)(scr + scro[4]);
    float* vu2   = (float*)(scr + scro[5]);
    double* part = (double*)(scr + scro[6]);
    double* red  = (double*)(scr + scro[7]);
    int*   modes = (int*)(scr + scro[8]);
    double* pA = part;
    double* pB = part + RG * 2;
    double* pC = part + RG * 4;
    double* pD = part + RG * 6;

    float* wt0 = wtall;
    float* wt1 = wt0 + 387072;
    float* wt2 = wt1 + 373248;
    float* wt3 = wt2 + 290304;
    float* wt4 = wt3 + 158976;
    float* wt5 = wt4 + 1296;
    float* wt6 = wt5 + 67392;
    float* wt7 = wt6 + 47520;

    // zero-init big buffers and scratch (modes default 0 = bf16)
    k_fill<<<4096, 256, 0, stream>>>((u16*)xin1, NX1, 0);
    k_fill<<<4096, 256, 0, stream>>>((u16*)xin2, NX2, 0);
    k_fill<<<4096, 256, 0, stream>>>((u16*)scr, (long)(scratch_need / 2), 0);

    // dtype detection for all tensor inputs (slot i for d_in[i])
    for (int i = 1; i < 23 && i < n_in; ++i) {
        k_detect<<<1, 256, 0, stream>>>(d_in[i], (long)in_sizes[i], modes + i);
    }

    k_wt<<<cdiv(387072, 256), 256, 0, stream>>>(d_in[7],  wt0, 224, 64, modes + 7);
    k_wt<<<cdiv(373248, 256), 256, 0, stream>>>(d_in[9],  wt1, 288, 48, modes + 9);
    k_wt<<<cdiv(290304, 256), 256, 0, stream>>>(d_in[11], wt2, 336, 32, modes + 11);
    k_wt<<<cdiv(158976, 256), 256, 0, stream>>>(d_in[13], wt3, 368, 16, modes + 13);
    k_wt<<<cdiv(1296, 256),   256, 0, stream>>>(d_in[15], wt4, 16, 3,   modes + 15);
    k_wt<<<cdiv(67392, 256),  256, 0, stream>>>(d_in[17], wt5, 78, 32,  modes + 17);
    k_wt<<<cdiv(47520, 256),  256, 0, stream>>>(d_in[19], wt6, 110, 16, modes + 19);
    k_wt<<<cdiv(1296, 256),   256, 0, stream>>>(d_in[21], wt7, 16, 3,   modes + 21);

    k_tcl<<<cdiv(NHALF, 256), 256, 0, stream>>>(fy,  32L * NHALF, xin1, NX1, 125, 32, NHALF, S1, modes + 3);
    k_tcl<<<cdiv(NHALF, 256), 256, 0, stream>>>(ctx, 32L * NHALF, xin1, NX1, 189, 32, NHALF, S1, modes + 6);
    k_tcl<<<cdiv(NFULL, 256), 256, 0, stream>>>(fyu, 16L * NFULL, xin2, NX2, 27, 16, NFULL, S2, modes + 5);

    k_down<<<cdiv(NHALF, 256), 256, 0, stream>>>(disp_up, disph, xin1, modes + 1);

    k_warp_cf<32><<<cdiv(NHALF, 256), 256, 0, stream>>>(fx, 32L * NHALF, disph, N3H, xin1, NX1, S1, 157, D1c, H1c, W1c, modes + 2);
    k_reduce_cl<<<RG, 256, 0, stream>>>(xin1, NX1, NHALF, S1, 157, 32, pA, modes + 31);
    k_reduce_cl<<<RG, 256, 0, stream>>>(fy, 32L * NHALF, 32L * NHALF, 1, 0, 1, pB, modes + 3);
    k_stats2<<<1, 256, 0, stream>>>(pA, pB, (double)(32L * NHALF), 32.0, red);

    k_cv1<<<(int)NHALF, 128, 0, stream>>>(xin1, red);

    k_conv<64, 2><<<cdiv(NHALF, 8),  256, 0, stream>>>(xin1, NX1, S1, wt0, d_in[8],  xin1, NX1, S1, 224, 224, 64, D1c, H1c, W1c, 0.02f, modes + 8);
    k_conv<48, 2><<<cdiv(NHALF, 10), 256, 0, stream>>>(xin1, NX1, S1, wt1, d_in[10], xin1, NX1, S1, 288, 288, 48, D1c, H1c, W1c, 0.02f, modes + 10);
    k_conv<32, 2><<<cdiv(NHALF, 16), 256, 0, stream>>>(xin1, NX1, S1, wt2, d_in[12], xin1, NX1, S1, 336, 336, 32, D1c, H1c, W1c, 0.02f, modes + 12);
    k_conv<16, 2><<<cdiv(NHALF, 32), 256, 0, stream>>>(xin1, NX1, S1, wt3, d_in[14], ctx16, NCTX16, 16, 0, 368, 16, D1c, H1c, W1c, 0.02f, modes + 14);
    k_conv_small<<<cdiv(NHALF, 256), 256, 0, stream>>>(ctx16, NCTX16, 16, 0, wt4, d_in[16], vel1, N3H, D1c, H1c, W1c, modes + 16);

    k_up_ctx<<<cdiv(NFULL, 256), 256, 0, stream>>>(ctx16, xin2);
    k_warp_dispup<<<cdiv(NFULL, 256), 256, 0, stream>>>(disp_up, vel1, du2, xin2, modes + 1);

    k_warp_cf<16><<<cdiv(NFULL, 256), 256, 0, stream>>>(fxu, 16L * NFULL, du2, N3F, xin2, NX2, S2, 43, D2c, H2c, W2c, modes + 4);
    k_reduce_cl<<<RG, 256, 0, stream>>>(xin2, NX2, NFULL, S2, 43, 16, pC, modes + 31);
    k_reduce_cl<<<RG, 256, 0, stream>>>(fyu, 16L * NFULL, 16L * NFULL, 1, 0, 1, pD, modes + 5);
    k_stats2<<<1, 256, 0, stream>>>(pC, pD, (double)(16L * NFULL), 16.0, red + 2);

    k_cv2<<<cdiv(NFULL, 8), 256, 0, stream>>>(xin2, red);

    k_conv<32, 2><<<cdiv(NFULL, 16), 256, 0, stream>>>(xin2, NX2, S2, wt5, d_in[18], xin2, NX2, S2, 78, 78, 32, D2c, H2c, W2c, 0.02f, modes + 18);
    k_conv<16, 2><<<cdiv(NFULL, 32), 256, 0, stream>>>(xin2, NX2, S2, wt6, d_in[20], xin2, NX2, S2, 110, 110, 16, D2c, H2c, W2c, 0.02f, modes + 20);
    k_conv_small<<<cdiv(NFULL, 256), 256, 0, stream>>>(xin2, NX2, S2, 110, wt7, d_in[22], vu2, N3F, D2c, H2c, W2c, modes + 22);

    // out dtype follows disp_up's detected mode
    k_final<<<cdiv(NFULL, 256), 256, 0, stream>>>(du2, vu2, disp_up, t_in, d_out, (long)out_size, modes + 1);
    k_fill_tail<<<2048, 256, 0, stream>>>(d_out, (long)vf_elems, (long)out_size, modes + 1);
}

// Round 7
// 5678.216 us; speedup vs baseline: 14.2341x; 14.2341x over previous
//
#include <hip/hip_runtime.h>
#include <hip/hip_bf16.h>

typedef __hip_bfloat16 bf16;
typedef unsigned short u16;
typedef unsigned int u32;

#define D1c 48
#define H1c 40
#define W1c 48
#define NHALF 92160L
#define D2c 96
#define H2c 80
#define W2c 96
#define NFULL 737280L
#define S1 368
#define S2 128
#define RG 512

#define NX1 (NHALF * S1)
#define NX2 (NFULL * S2)
#define NCTX16 (NHALF * 16)
#define N3H (NHALF * 3)
#define N3F (NFULL * 3)

typedef __attribute__((ext_vector_type(8))) short s8v;
typedef __attribute__((ext_vector_type(4))) float f4v;

__device__ __forceinline__ float bf2f(bf16 v){ return __bfloat162float(v); }
__device__ __forceinline__ float sf(float v){ return (v == v && fabsf(v) < 1e30f) ? v : 0.f; }
__device__ __forceinline__ bf16 f2bf(float v){ return __float2bfloat16(sf(v)); }
__device__ __forceinline__ long cl(long i, long n){ i = i < 0 ? 0 : i; return i >= n ? n - 1 : i; }
// mode-dispatched input load: 0 = bf16, 1 = f32
__device__ __forceinline__ float gld(const void* p, long i, int mode){
    return mode ? sf(((const float*)p)[i]) : sf(bf2f(((const bf16*)p)[i]));
}

// ---------------- dtype detection: one block per input ---------------------
__global__ void k_detect(const void* p, long nelem, int* flag) {
    long N = nelem < 4096 ? nelem : 4096;
    int tid = threadIdx.x;
    int nb = 0, nf = 0;
    for (long i = tid; i < N; i += 256) {
        float v = bf2f(((const bf16*)p)[i]);
        if (v == v && fabsf(v) <= 1e4f) nb++;
    }
    long M = N / 2;
    for (long i = tid; i < M; i += 256) {
        float v = ((const float*)p)[i];
        if (v == v && fabsf(v) <= 1e4f) nf += 2;
    }
    __shared__ int sb[256], sq[256];
    sb[tid] = nb; sq[tid] = nf;
    __syncthreads();
    for (int t = 128; t; t >>= 1) {
        if (tid < t) { sb[tid] += sb[tid + t]; sq[tid] += sq[tid + t]; }
        __syncthreads();
    }
    if (tid == 0) *flag = (sb[0] >= sq[0]) ? 0 : 1;
}

// ---------------- fills -----------------------------------------------------
__global__ void k_fill(u16* __restrict__ p, long n, u16 val) {
    long i = (long)blockIdx.x * 256 + threadIdx.x;
    long stride = (long)gridDim.x * 256;
    for (; i < n; i += stride) p[i] = val;
}
__global__ void k_fill_tail(void* out, long vf, long out_n, const int* __restrict__ modep) {
    int mode = *modep;
    long n = out_n - vf;
    if (n <= 0) return;
    long i = (long)blockIdx.x * 256 + threadIdx.x;
    long stride = (long)gridDim.x * 256;
    if (mode) { float* p = (float*)out + vf; for (; i < n; i += stride) p[i] = 0.f; }
    else      { u16*   p = (u16*)out + vf;   for (; i < n; i += stride) p[i] = 0; }
}

// ------- weight transpose: (co,ci,tap) -> (tap,ci,co) f32 (small convs) ----
__global__ void k_wt(const void* __restrict__ w, float* __restrict__ wt,
                     int Cin, int Cout, const int* __restrict__ modep) {
    int mode = *modep;
    long n = (long)Cin * Cout * 27;
    long i = (long)blockIdx.x * 256 + threadIdx.x;
    if (i >= n) return;
    int tap = (int)(i % 27); long r = i / 27;
    int ci = (int)(r % Cin); int co = (int)(r / Cin);
    wt[cl(((long)tap * Cin + ci) * Cout + co, n)] = gld(w, cl(i, n), mode);
}

// ------- MFMA weight repack: (co,ci,tap) -> [tap][chunk][co][32] bf16 ------
// zero-padded for ci >= Cin (Cin tails)
__global__ void k_wtb(const void* __restrict__ w, bf16* __restrict__ wtb,
                      int Cin, int Cout, int nchunk, const int* __restrict__ modep) {
    int mode = *modep;
    long n = 27L * nchunk * Cout * 32;
    long i = (long)blockIdx.x * 256 + threadIdx.x;
    if (i >= n) return;
    int kk = (int)(i & 31);
    long r = i >> 5;
    int co = (int)(r % Cout); r /= Cout;
    int ch = (int)(r % nchunk); int tap = (int)(r / nchunk);
    int ci = ch * 32 + kk;
    float v = (ci < Cin) ? gld(w, ((long)co * Cin + ci) * 27 + tap, mode) : 0.f;
    wtb[i] = f2bf(v);
}

// ------- channel-first [C][N] -> channel-last columns ----------------------
__global__ void k_tcl(const void* __restrict__ in, long nin,
                      bf16* __restrict__ out, long nout, int col0,
                      int C, long N, int stride, const int* __restrict__ modep) {
    int mode = *modep;
    long n = (long)blockIdx.x * 256 + threadIdx.x;
    if (n >= N) return;
    for (int c = 0; c < C; ++c)
        out[cl(n * stride + col0 + c, nout)] = f2bf(gld(in, cl((long)c * N + n, nin), mode));
}

// ------- antialiased x0.5 downsample taps ----------------------------------
__device__ __forceinline__ void down_taps(int i, int n_in, int j[4], float w[4]) {
    float s = 0.f;
    for (int k = 0; k < 4; ++k) {
        int jj = 2 * i - 1 + k;
        bool valid = (jj >= 0 && jj < n_in);
        j[k] = valid ? jj : 0;
        float b = (k == 0 || k == 3) ? 1.f : 3.f;
        w[k] = valid ? b : 0.f;
        s += w[k];
    }
    float inv = 1.f / fmaxf(s, 1e-6f);
    for (int k = 0; k < 4; ++k) w[k] *= inv;
}

// disp = resize(disp_up,0.5)*0.5 -> disph f32 + xin1 cols 221..223
__global__ void k_down(const void* __restrict__ dispup, float* __restrict__ disph,
                       bf16* __restrict__ xin1, const int* __restrict__ modep) {
    int mode = *modep;
    long p = (long)blockIdx.x * 256 + threadIdx.x;
    if (p >= NHALF) return;
    int x = (int)(p % W1c), y = (int)((p / W1c) % H1c), z = (int)(p / (W1c * H1c));
    int jz[4], jy[4], jx[4]; float wz[4], wy[4], wx[4];
    down_taps(z, D2c, jz, wz); down_taps(y, H2c, jy, wy); down_taps(x, W2c, jx, wx);
    for (int c = 0; c < 3; ++c) {
        float acc = 0.f;
        for (int a = 0; a < 4; ++a) {
            if (wz[a] == 0.f) continue;
            for (int b = 0; b < 4; ++b) {
                if (wy[b] == 0.f) continue;
                float wzy = wz[a] * wy[b];
                long base = (long)c * NFULL + ((long)jz[a] * H2c + jy[b]) * W2c;
                for (int d = 0; d < 4; ++d) {
                    if (wx[d] == 0.f) continue;
                    acc += wzy * wx[d] * gld(dispup, cl(base + jx[d], 3 * NFULL), mode);
                }
            }
        }
        acc = sf(acc * 0.5f);
        disph[cl(p * 3 + c, N3H)] = acc;
        xin1[cl(p * (long)S1 + 221 + c, NX1)] = f2bf(acc);
    }
}

// ------- trilinear warp, channel-first INPUT volume, zero pad --------------
template<int C>
__global__ void k_warp_cf(const void* __restrict__ vol, long nvol,
                          const float* __restrict__ coords, long ncoords,
                          bf16* __restrict__ dst, long ndst, int dstride, int col0,
                          int D, int H, int W, const int* __restrict__ modep) {
    int mode = *modep;
    const long N = (long)D * H * W;
    long p = (long)blockIdx.x * 256 + threadIdx.x;
    if (p >= N) return;
    int x = (int)(p % W), y = (int)((p / W) % H), z = (int)(p / ((long)W * H));
    float cz = z + sf(coords[cl(p * 3, ncoords)]);
    float cy = y + sf(coords[cl(p * 3 + 1, ncoords)]);
    float cx = x + sf(coords[cl(p * 3 + 2, ncoords)]);
    float acc[C];
    for (int c = 0; c < C; ++c) acc[c] = 0.f;
    float z0f = floorf(cz), y0f = floorf(cy), x0f = floorf(cx);
    int z0 = (int)z0f, y0 = (int)y0f, x0 = (int)x0f;
    float fz = cz - z0f, fy = cy - y0f, fx = cx - x0f;
    for (int dz = 0; dz < 2; ++dz) {
        int zi = z0 + dz; if (zi < 0 || zi >= D) continue;
        float wz = dz ? fz : 1.f - fz;
        for (int dy = 0; dy < 2; ++dy) {
            int yi = y0 + dy; if (yi < 0 || yi >= H) continue;
            float wzy = wz * (dy ? fy : 1.f - fy);
            for (int dx = 0; dx < 2; ++dx) {
                int xi = x0 + dx; if (xi < 0 || xi >= W) continue;
                float w = wzy * (dx ? fx : 1.f - fx);
                long idx = (long)(zi * H + yi) * W + xi;
                for (int c = 0; c < C; ++c) acc[c] += w * gld(vol, cl((long)c * N + idx, nvol), mode);
            }
        }
    }
    for (int c = 0; c < C; ++c) dst[cl(p * (long)dstride + col0 + c, ndst)] = f2bf(acc[c]);
}

// ------- two-stage deterministic reduction (sum, sumsq) --------------------
__global__ void k_reduce_cl(const void* __restrict__ base, long nbase, long rows,
                            int stride, int col0, int cn, double* __restrict__ part,
                            const int* __restrict__ modep) {
    int mode = *modep;
    long total = rows * cn;
    double s = 0.0, q = 0.0;
    long i = (long)blockIdx.x * 256 + threadIdx.x;
    long gs = (long)gridDim.x * 256;
    for (; i < total; i += gs) {
        long r = i / cn; int c = (int)(i - r * cn);
        float f = gld(base, cl(r * (long)stride + col0 + c, nbase), mode);
        s += f; q += (double)f * f;
    }
    __shared__ double ls[256], lq[256];
    ls[threadIdx.x] = s; lq[threadIdx.x] = q;
    __syncthreads();
    for (int t = 128; t; t >>= 1) {
        if (threadIdx.x < t) { ls[threadIdx.x] += ls[threadIdx.x + t]; lq[threadIdx.x] += lq[threadIdx.x + t]; }
        __syncthreads();
    }
    if (threadIdx.x == 0) { part[cl(blockIdx.x * 2, RG * 2)] = ls[0]; part[cl(blockIdx.x * 2 + 1, RG * 2)] = lq[0]; }
}

__global__ void k_stats2(const double* __restrict__ pa, const double* __restrict__ pb,
                         double n, double C, double* __restrict__ outm) {
    __shared__ double ls[256], lq[256];
    double s = 0.0, q = 0.0;
    for (int i = threadIdx.x; i < RG; i += 256) { s += pa[i * 2]; q += pa[i * 2 + 1]; }
    ls[threadIdx.x] = s; lq[threadIdx.x] = q;
    __syncthreads();
    for (int t = 128; t; t >>= 1) {
        if (threadIdx.x < t) { ls[threadIdx.x] += ls[threadIdx.x + t]; lq[threadIdx.x] += lq[threadIdx.x + t]; }
        __syncthreads();
    }
    double sa = ls[0], qa = lq[0];
    __syncthreads();
    s = 0.0; q = 0.0;
    for (int i = threadIdx.x; i < RG; i += 256) { s += pb[i * 2]; q += pb[i * 2 + 1]; }
    ls[threadIdx.x] = s; lq[threadIdx.x] = q;
    __syncthreads();
    for (int t = 128; t; t >>= 1) {
        if (threadIdx.x < t) { ls[threadIdx.x] += ls[threadIdx.x + t]; lq[threadIdx.x] += lq[threadIdx.x + t]; }
        __syncthreads();
    }
    if (threadIdx.x == 0) {
        double sb = ls[0], qb = lq[0];
        double va = (qa - sa * sa / n) / (n - 1.0);
        double vb = (qb - sb * sb / n) / (n - 1.0);
        va = va > 0.0 ? va : 0.0;
        vb = vb > 0.0 ? vb : 0.0;
        double sd = 0.5 * (sqrt(va) + sqrt(vb));
        sd = sd < 1e-6 ? 1e-6 : (sd > 1e9 ? 1e9 : sd);
        outm[0] = 0.5 * (sa / n + sb / n);
        outm[1] = 1.0 / (sd * sd * C);
    }
}

// ------- cost volume 1 (md=2, C=32) -> xin1 cols 0..124 --------------------
__global__ void k_cv1(bf16* __restrict__ xin1, const double* __restrict__ red) {
    __shared__ float fy[32];
    long p = blockIdx.x;
    float m = sf((float)red[0]), mult = sf((float)red[1]);
    int x = (int)(p % W1c), y = (int)((p / W1c) % H1c), z = (int)(p / (W1c * H1c));
    if (threadIdx.x < 32) fy[threadIdx.x] = sf(bf2f(xin1[cl(p * (long)S1 + 125 + threadIdx.x, NX1)])) - m;
    __syncthreads();
    int o = threadIdx.x;
    if (o >= 125) return;
    int dz = o / 25 - 2, dy = (o / 5) % 5 - 2, dx = o % 5 - 2;
    int z2 = z + dz, y2 = y + dy, x2 = x + dx;
    float cost = 0.f;
    if (z2 >= 0 && z2 < D1c && y2 >= 0 && y2 < H1c && x2 >= 0 && x2 < W1c) {
        long rb = ((long)(z2 * H1c + y2) * W1c + x2) * S1 + 157;
        float dot = 0.f;
        for (int c = 0; c < 32; ++c) dot += fy[c] * (sf(bf2f(xin1[cl(rb + c, NX1)])) - m);
        cost = dot * mult;
        cost = cost >= 0.f ? cost : 0.05f * cost;
    }
    xin1[cl(p * (long)S1 + o, NX1)] = f2bf(cost);
}

// ------- cost volume 2 (md=1, C=16) -> xin2 cols 0..26 ---------------------
__global__ void k_cv2(bf16* __restrict__ xin2, const double* __restrict__ red) {
    int t = threadIdx.x;
    int o = t % 32, vs = t / 32;
    long p = (long)blockIdx.x * 8 + vs;
    if (p >= NFULL || o >= 27) return;
    float m = sf((float)red[2]), mult = sf((float)red[3]);
    int x = (int)(p % W2c), y = (int)((p / W2c) % H2c), z = (int)(p / (W2c * H2c));
    int dz = o / 9 - 1, dy = (o / 3) % 3 - 1, dx = o % 3 - 1;
    int z2 = z + dz, y2 = y + dy, x2 = x + dx;
    float cost = 0.f;
    if (z2 >= 0 && z2 < D2c && y2 >= 0 && y2 < H2c && x2 >= 0 && x2 < W2c) {
        long fb = p * (long)S2 + 27;
        long wb = ((long)(z2 * H2c + y2) * W2c + x2) * S2 + 43;
        float dot = 0.f;
        for (int c = 0; c < 16; ++c)
            dot += (sf(bf2f(xin2[cl(fb + c, NX2)])) - m) * (sf(bf2f(xin2[cl(wb + c, NX2)])) - m);
        cost = dot * mult;
        cost = cost >= 0.f ? cost : 0.05f * cost;
    }
    xin2[cl(p * (long)S2 + o, NX2)] = f2bf(cost);
}

// ------- MFMA implicit-GEMM 3x3x3 conv, channel-last ----------------------
// wave = 16 voxels x Cout; K = 27 taps x nchunk*32 (weights zero-padded).
// A: lane holds A[m=lane&15][k=quad*8+j] -> one 16B load per K-step.
// B: lane holds B[k=quad*8+j][n=lane&15] from wtb[tap][ch][cout][32].
// D: row(m)=quad*4+reg, col(n)=lane&15.
template<int NT>
__global__ __launch_bounds__(256) void k_conv_mfma(
        const bf16* __restrict__ src, int sstride,
        const bf16* __restrict__ wtb, const void* __restrict__ bias,
        bf16* __restrict__ dst, int dstride, int dcol0,
        int nchunk, int Cout, int D, int H, int W, float slope,
        const int* __restrict__ bmodep) {
    const int bmode = *bmodep;
    const int tid = threadIdx.x;
    const int wave = tid >> 6, lane = tid & 63;
    const int quad = lane >> 4, nlo = lane & 15;
    const long mtile = (long)blockIdx.x * 4 + wave;
    const long HW = (long)H * W;
    const long va = mtile * 16 + nlo;     // A-operand voxel for this lane
    int xa = (int)(va % W); long rr = va / W;
    int ya = (int)(rr % H); int za = (int)(rr / H);

    f4v acc[NT];
    for (int nt = 0; nt < NT; ++nt) {
        float bv = gld(bias, nt * 16 + nlo, bmode);
        acc[nt][0] = bv; acc[nt][1] = bv; acc[nt][2] = bv; acc[nt][3] = bv;
    }

    for (int tap = 0; tap < 27; ++tap) {
        const int dz = tap / 9 - 1, dy = (tap / 3) % 3 - 1, dx = tap % 3 - 1;
        const int z2 = za + dz, y2 = ya + dy, x2 = xa + dx;
        const bool valid = (z2 >= 0 && z2 < D && y2 >= 0 && y2 < H && x2 >= 0 && x2 < W);
        const long nb = valid ? ((long)z2 * HW + (long)y2 * W + x2) : 0;
        const bf16* arow = src + nb * (long)sstride + quad * 8;
        const bf16* brow = wtb + ((long)tap * nchunk * Cout) * 32 + (long)nlo * 32 + quad * 8;
        for (int ch = 0; ch < nchunk; ++ch) {
            union { uint4 u; s8v v; } a;
            if (valid) a.u = *(const uint4*)(arow + ch * 32);
            else { a.u.x = 0; a.u.y = 0; a.u.z = 0; a.u.w = 0; }
            const bf16* bc = brow + (long)ch * Cout * 32;
            #pragma unroll
            for (int nt = 0; nt < NT; ++nt) {
                union { uint4 u; s8v v; } b;
                b.u = *(const uint4*)(bc + nt * 512);   // nt*16 cout rows * 32
                acc[nt] = __builtin_amdgcn_mfma_f32_16x16x32_bf16(a.v, b.v, acc[nt], 0, 0, 0);
            }
        }
    }
    const long vd = mtile * 16 + quad * 4;   // D rows for this lane
    for (int nt = 0; nt < NT; ++nt) {
        #pragma unroll
        for (int reg = 0; reg < 4; ++reg) {
            float v = acc[nt][reg];
            v = v >= 0.f ? v : v * slope;
            dst[(vd + reg) * (long)dstride + dcol0 + nt * 16 + nlo] = f2bf(v);
        }
    }
}

// ------- small conv: Cin=16 -> Cout=3, linear, f32 out ---------------------
__global__ void k_conv_small(const bf16* __restrict__ src, long nsrc, int sstride, int scol0,
                             const float* __restrict__ wt, const void* __restrict__ bias,
                             float* __restrict__ dst, long ndst, int D, int H, int W,
                             const int* __restrict__ bmodep) {
    int bmode = *bmodep;
    __shared__ float wl[27 * 16 * 3];
    for (int e = threadIdx.x; e < 27 * 16 * 3; e += 256) wl[e] = wt[e];
    __syncthreads();
    long N = (long)D * H * W;
    long p = (long)blockIdx.x * 256 + threadIdx.x;
    if (p >= N) return;
    int x = (int)(p % W), y = (int)((p / W) % H), z = (int)(p / ((long)W * H));
    float a0 = gld(bias, 0, bmode), a1 = gld(bias, 1, bmode), a2 = gld(bias, 2, bmode);
    for (int tap = 0; tap < 27; ++tap) {
        int dz = tap / 9 - 1, dy = (tap / 3) % 3 - 1, dx = tap % 3 - 1;
        int z2 = z + dz, y2 = y + dy, x2 = x + dx;
        if (z2 < 0 || z2 >= D || y2 < 0 || y2 >= H || x2 < 0 || x2 >= W) continue;
        long rb = ((long)(z2 * H + y2) * W + x2) * sstride + scol0;
        const float* w = wl + tap * 48;
        for (int c = 0; c < 16; ++c) {
            float f = bf2f(src[cl(rb + c, nsrc)]);
            a0 += f * w[c * 3]; a1 += f * w[c * 3 + 1]; a2 += f * w[c * 3 + 2];
        }
    }
    dst[cl(p * 3, ndst)] = sf(a0); dst[cl(p * 3 + 1, ndst)] = sf(a1); dst[cl(p * 3 + 2, ndst)] = sf(a2);
}

// ------- x2 upsample taps ---------------------------------------------------
__device__ __forceinline__ void up_taps(int i, int n, int& j0, int& j1, float& w0, float& w1) {
    if (i & 1) { j0 = i >> 1; j1 = j0 + 1; w0 = 0.75f; w1 = 0.25f; if (j1 >= n) { j1 = j0; w0 = 1.f; w1 = 0.f; } }
    else { j1 = i >> 1; j0 = j1 - 1; w0 = 0.25f; w1 = 0.75f; if (j0 < 0) { j0 = j1; w0 = 0.f; w1 = 1.f; } }
}

// ctx16 [NHALF][16] -> xin2 cols 59..74
__global__ void k_up_ctx(const bf16* __restrict__ in, bf16* __restrict__ xin2) {
    long p = (long)blockIdx.x * 256 + threadIdx.x;
    if (p >= NFULL) return;
    int x = (int)(p % W2c), y = (int)((p / W2c) % H2c), z = (int)(p / (W2c * H2c));
    int jz0, jz1, jy0, jy1, jx0, jx1; float wz0, wz1, wy0, wy1, wx0, wx1;
    up_taps(z, D1c, jz0, jz1, wz0, wz1);
    up_taps(y, H1c, jy0, jy1, wy0, wy1);
    up_taps(x, W1c, jx0, jx1, wx0, wx1);
    float acc[16];
    for (int c = 0; c < 16; ++c) acc[c] = 0.f;
    int jzs[2] = { jz0, jz1 }; float wzs[2] = { wz0, wz1 };
    int jys[2] = { jy0, jy1 }; float wys[2] = { wy0, wy1 };
    int jxs[2] = { jx0, jx1 }; float wxs[2] = { wx0, wx1 };
    for (int a = 0; a < 2; ++a) {
        if (wzs[a] == 0.f) continue;
        for (int b = 0; b < 2; ++b) {
            if (wys[b] == 0.f) continue;
            float wzy = wzs[a] * wys[b];
            for (int d = 0; d < 2; ++d) {
                if (wxs[d] == 0.f) continue;
                float w = wzy * wxs[d];
                long rb = ((long)(jzs[a] * H1c + jys[b]) * W1c + jxs[d]) * 16;
                for (int c = 0; c < 16; ++c) acc[c] += w * bf2f(in[cl(rb + c, NCTX16)]);
            }
        }
    }
    for (int c = 0; c < 16; ++c) xin2[cl(p * (long)S2 + 59 + c, NX2)] = f2bf(acc[c]);
}

// fused: velup = 2*up(vel1); du2 = warp(disp_up, velup) + velup; xin2 75..77
__global__ void k_warp_dispup(const void* __restrict__ dispup, const float* __restrict__ vel1,
                              float* __restrict__ du2, bf16* __restrict__ xin2,
                              const int* __restrict__ modep) {
    int mode = *modep;
    long p = (long)blockIdx.x * 256 + threadIdx.x;
    if (p >= NFULL) return;
    int x = (int)(p % W2c), y = (int)((p / W2c) % H2c), z = (int)(p / (W2c * H2c));
    int jz0, jz1, jy0, jy1, jx0, jx1; float wz0, wz1, wy0, wy1, wx0, wx1;
    up_taps(z, D1c, jz0, jz1, wz0, wz1);
    up_taps(y, H1c, jy0, jy1, wy0, wy1);
    up_taps(x, W1c, jx0, jx1, wx0, wx1);
    int jzs[2] = { jz0, jz1 }; float wzs[2] = { wz0, wz1 };
    int jys[2] = { jy0, jy1 }; float wys[2] = { wy0, wy1 };
    int jxs[2] = { jx0, jx1 }; float wxs[2] = { wx0, wx1 };
    float vu[3] = { 0.f, 0.f, 0.f };
    for (int a = 0; a < 2; ++a) {
        if (wzs[a] == 0.f) continue;
        for (int b = 0; b < 2; ++b) {
            if (wys[b] == 0.f) continue;
            float wzy = wzs[a] * wys[b];
            for (int d = 0; d < 2; ++d) {
                if (wxs[d] == 0.f) continue;
                float w = wzy * wxs[d];
                long rb = ((long)(jzs[a] * H1c + jys[b]) * W1c + jxs[d]) * 3;
                for (int c = 0; c < 3; ++c) vu[c] += w * sf(vel1[cl(rb + c, N3H)]);
            }
        }
    }
    for (int c = 0; c < 3; ++c) vu[c] = sf(vu[c] * 2.f);
    float cz = z + vu[0], cy = y + vu[1], cx = x + vu[2];
    float acc[3] = { 0.f, 0.f, 0.f };
    float z0f = floorf(cz), y0f = floorf(cy), x0f = floorf(cx);
    int z0 = (int)z0f, y0 = (int)y0f, x0 = (int)x0f;
    float fz = cz - z0f, fy = cy - y0f, fx = cx - x0f;
    for (int dz = 0; dz < 2; ++dz) {
        int zi = z0 + dz; if (zi < 0 || zi >= D2c) continue;
        float wz = dz ? fz : 1.f - fz;
        for (int dy = 0; dy < 2; ++dy) {
            int yi = y0 + dy; if (yi < 0 || yi >= H2c) continue;
            float wzy = wz * (dy ? fy : 1.f - fy);
            for (int dx = 0; dx < 2; ++dx) {
                int xi = x0 + dx; if (xi < 0 || xi >= W2c) continue;
                float w = wzy * (dx ? fx : 1.f - fx);
                long idx = (long)(zi * H2c + yi) * W2c + xi;
                for (int c = 0; c < 3; ++c) acc[c] += w * gld(dispup, cl((long)c * NFULL + idx, 3 * NFULL), mode);
            }
        }
    }
    for (int c = 0; c < 3; ++c) {
        float v = sf(acc[c] + vu[c]);
        du2[cl(p * 3 + c, N3F)] = v;
        xin2[cl(p * (long)S2 + 75 + c, NX2)] = f2bf(v);
    }
}

// robust t decode (handles bf16-stored or f32-stored scalar)
__device__ __forceinline__ float decode_t(const u16* tp) {
    u16 b0 = tp[0], b1 = tp[1];
    union { u32 i; float f; } a, b;
    a.i = ((u32)b0) << 16;
    b.i = ((u32)b1 << 16) | b0;
    float ta = a.f, tb = b.f;
    bool okA = (ta == ta) && ta >= 0.f && ta < 0.75f;
    bool okB = (tb == tb) && tb >= 0.f && tb < 0.75f;
    return okB ? tb : (okA ? ta : 0.f);
}

// vf = (warp(du2, vu2) + vu2 - disp_up) / (1 - t); out mode-dispatched
__global__ void k_final(const float* __restrict__ du2, const float* __restrict__ vu2,
                        const void* __restrict__ dispup, const u16* __restrict__ tptr,
                        void* __restrict__ out, long out_n, const int* __restrict__ modep) {
    int mode = *modep;
    long p = (long)blockIdx.x * 256 + threadIdx.x;
    if (p >= NFULL) return;
    float t = decode_t(tptr);
    float den = 1.f - t;
    if (fabsf(den) < 1e-6f) den = 1e-6f;
    float inv = 1.f / den;
    int x = (int)(p % W2c), y = (int)((p / W2c) % H2c), z = (int)(p / (W2c * H2c));
    float cz = z + sf(vu2[cl(p * 3, N3F)]);
    float cy = y + sf(vu2[cl(p * 3 + 1, N3F)]);
    float cx = x + sf(vu2[cl(p * 3 + 2, N3F)]);
    float acc[3] = { 0.f, 0.f, 0.f };
    float z0f = floorf(cz), y0f = floorf(cy), x0f = floorf(cx);
    int z0 = (int)z0f, y0 = (int)y0f, x0 = (int)x0f;
    float fz = cz - z0f, fy = cy - y0f, fx = cx - x0f;
    for (int dz = 0; dz < 2; ++dz) {
        int zi = z0 + dz; if (zi < 0 || zi >= D2c) continue;
        float wz = dz ? fz : 1.f - fz;
        for (int dy = 0; dy < 2; ++dy) {
            int yi = y0 + dy; if (yi < 0 || yi >= H2c) continue;
            float wzy = wz * (dy ? fy : 1.f - fy);
            for (int dx = 0; dx < 2; ++dx) {
                int xi = x0 + dx; if (xi < 0 || xi >= W2c) continue;
                float w = wzy * (dx ? fx : 1.f - fx);
                long rb = ((long)(zi * H2c + yi) * W2c + xi) * 3;
                for (int c = 0; c < 3; ++c) acc[c] += w * sf(du2[cl(rb + c, N3F)]);
            }
        }
    }
    for (int c = 0; c < 3; ++c) {
        float v = (acc[c] + sf(vu2[cl(p * 3 + c, N3F)]) - gld(dispup, cl((long)c * NFULL + p, 3 * NFULL), mode)) * inv;
        long oi = cl((long)c * NFULL + p, out_n);
        if (mode) ((float*)out)[oi] = sf(v);
        else      ((bf16*)out)[oi] = f2bf(v);
    }
}

static inline int cdiv(long a, long b) { return (int)((a + b - 1) / b); }

extern "C" void kernel_launch(void* const* d_in, const int* in_sizes, int n_in,
                              void* d_out, int out_size, void* d_ws, size_t ws_size,
                              hipStream_t stream) {
    const u16* t_in = (const u16*)d_in[0];
    const void* disp_up = d_in[1];
    const void* fx  = d_in[2];
    const void* fy  = d_in[3];
    const void* fxu = d_in[4];
    const void* fyu = d_in[5];
    const void* ctx = d_in[6];

    const size_t XIN1_B = (size_t)NX1 * 2;
    const size_t XIN2_B = (size_t)NX2 * 2;
    const size_t base_need = XIN1_B + XIN2_B;
    const size_t base_pad = (base_need + 255) & ~(size_t)255;
    const size_t vf_elems = 3UL * NFULL;

    // wtb sizes (bf16 elements): 27 * nchunk * Cout * 32
    const long WTB0 = 387072;  // 224->64, 7ch
    const long WTB1 = 373248;  // 288->48, 9ch
    const long WTB2 = 304128;  // 336->32, 11ch
    const long WTB3 = 165888;  // 368->16, 12ch
    const long WTB5 = 82944;   // 78->32, 3ch
    const long WTB6 = 55296;   // 110->16, 4ch
    const long WTB_TOT = WTB0 + WTB1 + WTB2 + WTB3 + WTB5 + WTB6; // 1,368,576

    size_t scro[11];
    {
        size_t o = 0;
        auto al = [&](size_t bytes) { size_t r = o; o = (o + bytes + 255) & ~(size_t)255; return r; };
        scro[0] = al((size_t)WTB_TOT * 2);      // WTB (bf16, mfma layout)
        scro[1] = al(2UL * 1296 * 4);           // WT f32 (two small convs)
        scro[2] = al((size_t)NCTX16 * 2);       // CTX16
        scro[3] = al((size_t)N3H * 4);          // VEL1
        scro[4] = al((size_t)N3H * 4);          // DISPH
        scro[5] = al((size_t)N3F * 4);          // DU2
        scro[6] = al((size_t)N3F * 4);          // VU2
        scro[7] = al(4UL * RG * 2 * 8);         // partials
        scro[8] = al(16 * 8);                   // RED
        scro[9] = al(32 * 4);                   // MODES
        scro[10] = o;
    }
    const size_t scratch_need = scro[10];
    const size_t tail_avail = ((size_t)out_size > vf_elems) ? ((size_t)out_size - vf_elems) * 2 : 0;

    char* scr = nullptr;
    if (ws_size >= base_pad + scratch_need) {
        scr = (char*)d_ws + base_pad;
    } else if (ws_size >= base_need && tail_avail >= scratch_need) {
        scr = (char*)d_out + vf_elems * 2;
    }
    if (scr == nullptr) {
        k_fill<<<2048, 256, 0, stream>>>((u16*)d_out, (long)out_size, 0x49A0);
        return;
    }

    char* ws = (char*)d_ws;
    bf16*  xin1  = (bf16*)ws;
    bf16*  xin2  = (bf16*)(ws + XIN1_B);
    bf16*  wtball = (bf16*)(scr + scro[0]);
    float* wtf   = (float*)(scr + scro[1]);
    bf16*  ctx16 = (bf16*)(scr + scro[2]);
    float* vel1  = (float*)(scr + scro[3]);
    float* disph = (float*)(scr + scro[4]);
    float* du2   = (float*)(scr + scro[5]);
    float* vu2   = (float*)(scr + scro[6]);
    double* part = (double*)(scr + scro[7]);
    double* red  = (double*)(scr + scro[8]);
    int*   modes = (int*)(scr + scro[9]);
    double* pA = part;
    double* pB = part + RG * 2;
    double* pC = part + RG * 4;
    double* pD = part + RG * 6;

    bf16* wtb0 = wtball;
    bf16* wtb1 = wtb0 + WTB0;
    bf16* wtb2 = wtb1 + WTB1;
    bf16* wtb3 = wtb2 + WTB2;
    bf16* wtb5 = wtb3 + WTB3;
    bf16* wtb6 = wtb5 + WTB5;
    float* wt4 = wtf;
    float* wt7 = wtf + 1296;

    // zero-init big buffers and scratch (modes default 0 = bf16)
    k_fill<<<4096, 256, 0, stream>>>((u16*)xin1, NX1, 0);
    k_fill<<<4096, 256, 0, stream>>>((u16*)xin2, NX2, 0);
    k_fill<<<4096, 256, 0, stream>>>((u16*)scr, (long)(scratch_need / 2), 0);

    // dtype detection for all tensor inputs
    for (int i = 1; i < 23 && i < n_in; ++i) {
        k_detect<<<1, 256, 0, stream>>>(d_in[i], (long)in_sizes[i], modes + i);
    }

    // MFMA weight repack (bf16, zero-padded K tails)
    k_wtb<<<cdiv(WTB0, 256), 256, 0, stream>>>(d_in[7],  wtb0, 224, 64, 7,  modes + 7);
    k_wtb<<<cdiv(WTB1, 256), 256, 0, stream>>>(d_in[9],  wtb1, 288, 48, 9,  modes + 9);
    k_wtb<<<cdiv(WTB2, 256), 256, 0, stream>>>(d_in[11], wtb2, 336, 32, 11, modes + 11);
    k_wtb<<<cdiv(WTB3, 256), 256, 0, stream>>>(d_in[13], wtb3, 368, 16, 12, modes + 13);
    k_wtb<<<cdiv(WTB5, 256), 256, 0, stream>>>(d_in[17], wtb5, 78,  32, 3,  modes + 17);
    k_wtb<<<cdiv(WTB6, 256), 256, 0, stream>>>(d_in[19], wtb6, 110, 16, 4,  modes + 19);
    // f32 weights for the two small convs
    k_wt<<<cdiv(1296, 256), 256, 0, stream>>>(d_in[15], wt4, 16, 3, modes + 15);
    k_wt<<<cdiv(1296, 256), 256, 0, stream>>>(d_in[21], wt7, 16, 3, modes + 21);

    k_tcl<<<cdiv(NHALF, 256), 256, 0, stream>>>(fy,  32L * NHALF, xin1, NX1, 125, 32, NHALF, S1, modes + 3);
    k_tcl<<<cdiv(NHALF, 256), 256, 0, stream>>>(ctx, 32L * NHALF, xin1, NX1, 189, 32, NHALF, S1, modes + 6);
    k_tcl<<<cdiv(NFULL, 256), 256, 0, stream>>>(fyu, 16L * NFULL, xin2, NX2, 27, 16, NFULL, S2, modes + 5);

    k_down<<<cdiv(NHALF, 256), 256, 0, stream>>>(disp_up, disph, xin1, modes + 1);

    k_warp_cf<32><<<cdiv(NHALF, 256), 256, 0, stream>>>(fx, 32L * NHALF, disph, N3H, xin1, NX1, S1, 157, D1c, H1c, W1c, modes + 2);
    k_reduce_cl<<<RG, 256, 0, stream>>>(xin1, NX1, NHALF, S1, 157, 32, pA, modes + 31);
    k_reduce_cl<<<RG, 256, 0, stream>>>(fy, 32L * NHALF, 32L * NHALF, 1, 0, 1, pB, modes + 3);
    k_stats2<<<1, 256, 0, stream>>>(pA, pB, (double)(32L * NHALF), 32.0, red);

    k_cv1<<<(int)NHALF, 128, 0, stream>>>(xin1, red);

    // fl1 dense block — MFMA implicit GEMM (mtiles/4 blocks)
    k_conv_mfma<4><<<1440, 256, 0, stream>>>(xin1, S1, wtb0, d_in[8],  xin1, S1, 224, 7,  64, D1c, H1c, W1c, 0.02f, modes + 8);
    k_conv_mfma<3><<<1440, 256, 0, stream>>>(xin1, S1, wtb1, d_in[10], xin1, S1, 288, 9,  48, D1c, H1c, W1c, 0.02f, modes + 10);
    k_conv_mfma<2><<<1440, 256, 0, stream>>>(xin1, S1, wtb2, d_in[12], xin1, S1, 336, 11, 32, D1c, H1c, W1c, 0.02f, modes + 12);
    k_conv_mfma<1><<<1440, 256, 0, stream>>>(xin1, S1, wtb3, d_in[14], ctx16, 16, 0, 12, 16, D1c, H1c, W1c, 0.02f, modes + 14);
    k_conv_small<<<cdiv(NHALF, 256), 256, 0, stream>>>(ctx16, NCTX16, 16, 0, wt4, d_in[16], vel1, N3H, D1c, H1c, W1c, modes + 16);

    k_up_ctx<<<cdiv(NFULL, 256), 256, 0, stream>>>(ctx16, xin2);
    k_warp_dispup<<<cdiv(NFULL, 256), 256, 0, stream>>>(disp_up, vel1, du2, xin2, modes + 1);

    k_warp_cf<16><<<cdiv(NFULL, 256), 256, 0, stream>>>(fxu, 16L * NFULL, du2, N3F, xin2, NX2, S2, 43, D2c, H2c, W2c, modes + 4);
    k_reduce_cl<<<RG, 256, 0, stream>>>(xin2, NX2, NFULL, S2, 43, 16, pC, modes + 31);
    k_reduce_cl<<<RG, 256, 0, stream>>>(fyu, 16L * NFULL, 16L * NFULL, 1, 0, 1, pD, modes + 5);
    k_stats2<<<1, 256, 0, stream>>>(pC, pD, (double)(16L * NFULL), 16.0, red + 2);

    k_cv2<<<cdiv(NFULL, 8), 256, 0, stream>>>(xin2, red);

    // fl2 block — MFMA
    k_conv_mfma<2><<<11520, 256, 0, stream>>>(xin2, S2, wtb5, d_in[18], xin2, S2, 78,  3, 32, D2c, H2c, W2c, 0.02f, modes + 18);
    k_conv_mfma<1><<<11520, 256, 0, stream>>>(xin2, S2, wtb6, d_in[20], xin2, S2, 110, 4, 16, D2c, H2c, W2c, 0.02f, modes + 20);
    k_conv_small<<<cdiv(NFULL, 256), 256, 0, stream>>>(xin2, NX2, S2, 110, wt7, d_in[22], vu2, N3F, D2c, H2c, W2c, modes + 22);

    // out dtype follows disp_up's detected mode
    k_final<<<cdiv(NFULL, 256), 256, 0, stream>>>(du2, vu2, disp_up, t_in, d_out, (long)out_size, modes + 1);
    k_fill_tail<<<2048, 256, 0, stream>>>(d_out, (long)vf_elems, (long)out_size, modes + 1);
}